// Round 1
// baseline (108.672 us; speedup 1.0000x reference)
//
#include <hip/hip_runtime.h>

// Problem constants (from reference): B=256, T=256, H=768, S=130
#define BB 256
#define TT 256
#define HH 768
#define SS 130
#define SP 144   // S padded to 9 MFMA n-tiles of 16
#define KC 64    // K-chunk per staging step (2 MFMA k-halves of 32)
#define AS 72    // A_lds row stride in ushorts (64 bf16 + 8 pad = 144 B, 16B-aligned)
#define BS 72    // B_lds row stride in ushorts
#define CS 148   // C_lds row stride in floats (pad vs 144 to break write conflicts)

typedef __attribute__((ext_vector_type(8))) __bf16 bf16x8;
typedef __attribute__((ext_vector_type(4))) float f32x4;

// fp32 -> bf16 round-to-nearest-even (inputs are finite random normals; no NaN path needed)
__device__ __forceinline__ unsigned short f2bf(float f) {
    unsigned x = __builtin_bit_cast(unsigned, f);
    x = (x + 0x7FFFu + ((x >> 16) & 1u)) >> 16;
    return (unsigned short)x;
}

__global__ __launch_bounds__(512, 1)
void fused_slot_merge_kernel(const float* __restrict__ hidden,
                             const float* __restrict__ W,
                             const float* __restrict__ bias,
                             const int*   __restrict__ seg,
                             float* __restrict__ out)
{
    // LDS: staging (A: 36864 B, B: 20736 B) aliased under C (256*148*4 = 151552 B)
    __shared__ __align__(16) char smem[151552];
    __shared__ int seg_lds[TT];

    unsigned short* A_us = (unsigned short*)smem;              // [256][AS] bf16
    unsigned short* B_us = (unsigned short*)(smem + 36864);    // [SP][BS] bf16 (W^T)
    float* C_lds = (float*)smem;                               // [256][CS] fp32 logits

    const int b    = blockIdx.x;
    const int tid  = threadIdx.x;
    const int wave = tid >> 6;
    const int lane = tid & 63;

    // stage segment ids for this batch row
    if (tid < TT) seg_lds[tid] = seg[b * TT + tid];

    // zero the padded B rows s=130..143 once (rows are contiguous: 14*72 ushorts = 504 uints)
    {
        unsigned* bz = (unsigned*)(B_us + SS * BS);
        if (tid < 504) bz[tid] = 0u;
    }

    const float* Arow = hidden + (size_t)b * (TT + 1) * HH + HH;  // skip [CLS] token

    f32x4 acc[2][9];
    #pragma unroll
    for (int i = 0; i < 2; ++i)
        #pragma unroll
        for (int j = 0; j < 9; ++j)
            acc[i][j] = (f32x4){0.f, 0.f, 0.f, 0.f};

    const int quad = tid & 15;   // which float4 of the 64-wide k chunk
    const int trow = tid >> 4;   // 0..31, token row group

    for (int k0 = 0; k0 < HH; k0 += KC) {
        // ---- stage A: 256 tokens x 64 k, fp32 -> bf16 ----
        #pragma unroll
        for (int r = 0; r < 8; ++r) {
            int t = trow + 32 * r;
            const float4 v = *(const float4*)(Arow + (size_t)t * HH + k0 + quad * 4);
            unsigned lo = (unsigned)f2bf(v.x) | ((unsigned)f2bf(v.y) << 16);
            unsigned hi = (unsigned)f2bf(v.z) | ((unsigned)f2bf(v.w) << 16);
            *(uint2*)(A_us + t * AS + quad * 4) = make_uint2(lo, hi);
        }
        // ---- stage W^T: 32 k-pairs x 130 s, fp32 -> bf16 ----
        for (int i = tid; i < 32 * SS; i += 512) {
            int s  = i % SS;
            int kp = i / SS;
            float x = W[(size_t)(k0 + 2 * kp)     * SS + s];
            float y = W[(size_t)(k0 + 2 * kp + 1) * SS + s];
            unsigned u = (unsigned)f2bf(x) | ((unsigned)f2bf(y) << 16);
            *(unsigned*)(B_us + s * BS + kp * 2) = u;
        }
        __syncthreads();

        // ---- MFMA: each wave owns 32 tokens (2 m-tiles) x 9 n-tiles ----
        #pragma unroll
        for (int kh = 0; kh < 2; ++kh) {
            const int kof = kh * 32 + (lane >> 4) * 8;  // ushort offset of this lane's 8 k-elems
            bf16x8 af0 = *(const bf16x8*)(A_us + (wave * 32 +      (lane & 15)) * AS + kof);
            bf16x8 af1 = *(const bf16x8*)(A_us + (wave * 32 + 16 + (lane & 15)) * AS + kof);
            #pragma unroll
            for (int nt = 0; nt < 9; ++nt) {
                bf16x8 bfr = *(const bf16x8*)(B_us + (nt * 16 + (lane & 15)) * BS + kof);
                acc[0][nt] = __builtin_amdgcn_mfma_f32_16x16x32_bf16(af0, bfr, acc[0][nt], 0, 0, 0);
                acc[1][nt] = __builtin_amdgcn_mfma_f32_16x16x32_bf16(af1, bfr, acc[1][nt], 0, 0, 0);
            }
        }
        __syncthreads();  // staging buffers reusable next step
    }

    // ---- write logits to LDS (aliases staging; last reads are behind the barrier above) ----
    #pragma unroll
    for (int mt = 0; mt < 2; ++mt) {
        const int tbase = wave * 32 + mt * 16 + 4 * (lane >> 4);  // D row = (lane>>4)*4 + r
        const int s     = lane & 15;                               // D col = lane&15
        #pragma unroll
        for (int nt = 0; nt < 9; ++nt) {
            #pragma unroll
            for (int r = 0; r < 4; ++r) {
                C_lds[(tbase + r) * CS + nt * 16 + s] = acc[mt][nt][r];
            }
        }
    }
    __syncthreads();

    // ---- phase 2: contiguous-run segment mean + bias, transposed write [B,S,T] ----
    if (tid < SS) {
        const float bs = bias[tid];
        float* orow = out + ((size_t)b * SS + tid) * TT;
        float a = 0.f;
        int cnt = 0, wprev = -1;
        int cur = seg_lds[0];
        for (int t = 0; t < TT; ++t) {
            a += C_lds[t * CS + tid];
            ++cnt;
            int nxt = (t < TT - 1) ? seg_lds[t + 1] : -1;
            if (nxt != cur) {
                for (int wz = wprev + 1; wz < cur; ++wz) orow[wz] = 0.f;  // empty segments -> 0
                orow[cur] = a / (float)cnt + bs;
                wprev = cur; cur = nxt; a = 0.f; cnt = 0;
            }
        }
        for (int wz = wprev + 1; wz < TT; ++wz) orow[wz] = 0.f;
    }
}

extern "C" void kernel_launch(void* const* d_in, const int* in_sizes, int n_in,
                              void* d_out, int out_size, void* d_ws, size_t ws_size,
                              hipStream_t stream)
{
    const float* hidden = (const float*)d_in[0];  // [256, 257, 768] f32
    const float* W      = (const float*)d_in[1];  // [768, 130] f32
    const float* bias   = (const float*)d_in[2];  // [130] f32
    const int*   seg    = (const int*)d_in[3];    // [256, 256] i32 (row-sorted)
    float* out = (float*)d_out;                   // [256, 130, 256] f32

    (void)in_sizes; (void)n_in; (void)d_ws; (void)ws_size; (void)out_size;

    fused_slot_merge_kernel<<<dim3(BB), dim3(512), 0, stream>>>(hidden, W, bias, seg, out);
}